// Round 3
// baseline (623.308 us; speedup 1.0000x reference)
//
#include <hip/hip_runtime.h>
#include <stdint.h>

#define BB 4
#define CC 256
#define HH 256
#define WW 256
#define TH 16                 // output rows per block
#define TR 20                 // rows incl 2+2 halo
#define NCH 8                 // channels per block (even: 2-deep pipeline)
#define NTILES (HH/TH)        // 16
#define NCHUNKS (CC/NCH)      // 32

// ---------------- kernel 0: zero accumulators (ws is poisoned 0xAA) ----------------
__global__ void k_init(unsigned int* p) {
    if (threadIdx.x < 8) p[threadIdx.x] = 0;   // 2 doubles (lsum) + 4 uints (counts)
}

// ---------------- kernel 1: per-pixel code byte: lab | good<<2 | edge<<3 ----------------
__global__ void k_code(const float* __restrict__ cls, const int* __restrict__ gt,
                       unsigned char* __restrict__ code) {
    int i = blockIdx.x * 256 + threadIdx.x;        // [0, B*H*W)
    int w = i & 255, h = (i >> 8) & 255;
    int b = i >> 16;
    int g = gt[i];
    float c0 = cls[((b*2 + 0)*HH + h)*WW + w];
    float c1 = cls[((b*2 + 1)*HH + h)*WW + w];
    int pred = (c1 > c0) ? 1 : 0;                  // jnp.argmax tie -> 0
    int ud = (h < HH-5) ? (gt[i + 5*WW] != g) : 0; // pad at END of axis (matches jnp.pad)
    int lr = (w < WW-5) ? (gt[i + 5] != g) : 0;
    int edge = (ud | lr | (g == -1)) ? 1 : 0;
    int lab = (g == 0) ? 0 : ((g == 1) ? 1 : 2);
    int good = (lab < 2 && pred == g) ? 1 : 0;
    code[i] = (unsigned char)(lab | (good << 2) | (edge << 3));
}

// ---- DPP halo exchange: value from lane l-1 (row_shr semantics: dst[n]=src[n-1]) ----
// wave_shr1 = 0x138, wave_shl1 = 0x130; bound_ctrl=true => out-of-wave source reads 0.
__device__ __forceinline__ float dpp_from_left(float x) {     // lane0 -> 0
    int r = __builtin_amdgcn_update_dpp(0, __builtin_bit_cast(int, x), 0x138, 0xf, 0xf, true);
    return __builtin_bit_cast(float, r);
}
__device__ __forceinline__ float dpp_from_right(float x) {    // lane63 -> 0
    int r = __builtin_amdgcn_update_dpp(0, __builtin_bit_cast(int, x), 0x130, 0xf, 0xf, true);
    return __builtin_bit_cast(float, r);
}
__device__ __forceinline__ int dpp_from_left_i(int x) {
    return __builtin_amdgcn_update_dpp(0, x, 0x138, 0xf, 0xf, true);
}
__device__ __forceinline__ int dpp_from_right_i(int x) {
    return __builtin_amdgcn_update_dpp(0, x, 0x130, 0xf, 0xf, true);
}

__device__ __forceinline__ float f4get(const float4& v, int j) {
    switch (j) { case 0: return v.x; case 1: return v.y; case 2: return v.z; default: return v.w; }
}

// horizontal 5-window sums over 4 cols/lane (cols 4l..4l+3), halo via DPP (pure VALU)
__device__ __forceinline__ void hwin_f(const float* vs, float* S) {
    float eL0 = dpp_from_left(vs[2]);    // col 4l-2
    float eL1 = dpp_from_left(vs[3]);    // col 4l-1
    float eR0 = dpp_from_right(vs[0]);   // col 4l+4
    float eR1 = dpp_from_right(vs[1]);   // col 4l+5
    float m = vs[1] + vs[2];
    float core = vs[0] + m;              // vs0+vs1+vs2
    float c2 = m + vs[3];                // vs1+vs2+vs3
    S[0] = core + eL0 + eL1;
    S[1] = core + vs[3] + eL1;
    S[2] = core + vs[3] + eR0;
    S[3] = c2 + eR0 + eR1;
}

__device__ __forceinline__ void hwin_i(const int* vs, int* S) {
    int eL0 = dpp_from_left_i(vs[2]);
    int eL1 = dpp_from_left_i(vs[3]);
    int eR0 = dpp_from_right_i(vs[0]);
    int eR1 = dpp_from_right_i(vs[1]);
    int m = vs[1] + vs[2];
    int core = vs[0] + m;
    int c2 = m + vs[3];
    S[0] = core + eL0 + eL1;
    S[1] = core + vs[3] + eL1;
    S[2] = core + vs[3] + eR0;
    S[3] = c2 + eR0 + eR1;
}

// ---------------- kernel 2: the heavy pass (also computes global counts on chunk==0) ----
// grid = B * NTILES * NCHUNKS = 4*16*32 = 2048 blocks, 256 threads.
// wave w: output rows R0+4w..R0+4w+3; lane l: cols 4l..4l+3 (full 256-wide row per wave).
__global__ __launch_bounds__(256, 3) void k_loss(const float* __restrict__ F,
                                                 const unsigned char* __restrict__ code,
                                                 double* __restrict__ lsum,
                                                 unsigned int* __restrict__ cnts) {
    __shared__ unsigned int csh[TR*64];   // code tile, 20 rows x 256 bytes
    __shared__ float red[8];
    const int t = threadIdx.x, w = t >> 6, l = t & 63;
    const int bx = blockIdx.x;
    const int chunk = bx & (NCHUNKS - 1);
    const int tile = (bx >> 5) & (NTILES - 1);
    const int b = bx >> 9;
    const int R0 = tile * TH;

    // ---- stage code tile; out-of-image rows get lab=2 (contributes nothing) ----
    for (int idx = t; idx < TR*64; idx += 256) {
        int rr = idx >> 6, grow = R0 - 2 + rr;
        unsigned int v = 0x02020202u;
        if ((unsigned)grow < HH) v = ((const unsigned int*)code)[(b*HH + grow)*64 + (idx & 63)];
        csh[idx] = v;
    }
    __syncthreads();

    const int rbase = R0 + 4*w - 2;   // wave's first input row (global)

    // ---- per-thread mask build for its 8 input rows x 4 cols ----
    float fm0[8][4], fm1[8][4];       // 0/1 floats: (lab==c)&good per (row,col)
    unsigned int mgd[8], mcls[8];     // bit masks: good-class (bits0-3 c0, 4-7 c1), class
    unsigned int cw2[4];              // center rows' raw code words (rows 2..5)
    #pragma unroll
    for (int rr = 0; rr < 8; rr++) {
        unsigned int u = csh[(4*w + rr)*64 + l];
        unsigned int mg = 0, mc = 0;
        #pragma unroll
        for (int j = 0; j < 4; j++) {
            unsigned int q = (u >> (8*j)) & 255u;
            unsigned int lab2 = q & 3u, good = (q >> 2) & 1u;
            unsigned int c0 = (lab2 == 0u) ? 1u : 0u;
            unsigned int c1 = (lab2 == 1u) ? 1u : 0u;
            mg |= (c0 & good) << j;
            mg |= (c1 & good) << (4 + j);
            mc |= c0 << j;
            mc |= c1 << (4 + j);
            fm0[rr][j] = (float)(c0 & good);
            fm1[rr][j] = (float)(c1 & good);
        }
        mgd[rr] = mg; mcls[rr] = mc;
        if (rr >= 2 && rr <= 5) cw2[rr - 2] = u;
    }

    // ---- counts / wq precompute (channel-invariant) ----
    float wq[16];
    unsigned int mse0bits = 0, mse1bits = 0, labbits = 0;
    int ccal0 = 0, ccal1 = 0, cms0 = 0, cms1 = 0;
    #pragma unroll
    for (int o = 0; o < 4; o++) {
        int vg0[4] = {0,0,0,0}, vg1[4] = {0,0,0,0}, vc0[4] = {0,0,0,0}, vc1[4] = {0,0,0,0};
        #pragma unroll
        for (int k = 0; k < 5; k++) {
            unsigned int mg = mgd[o+k], mc = mcls[o+k];
            #pragma unroll
            for (int j = 0; j < 4; j++) {
                vg0[j] += (mg >> j) & 1;  vg1[j] += (mg >> (4+j)) & 1;
                vc0[j] += (mc >> j) & 1;  vc1[j] += (mc >> (4+j)) & 1;
            }
        }
        int bg0[4], bg1[4], bc0[4], bc1[4];
        hwin_i(vg0, bg0); hwin_i(vg1, bg1);
        hwin_i(vc0, bc0); hwin_i(vc1, bc1);
        #pragma unroll
        for (int j = 0; j < 4; j++) {
            unsigned int q = (cw2[o] >> (8*j)) & 255u;
            int lab2 = q & 3, good = (q >> 2) & 1, edge = (q >> 3) & 1;
            int bcl = (lab2 == 1) ? bc1[j] : bc0[j];
            int bgl = (lab2 == 1) ? bg1[j] : bg0[j];
            int ccls = bcl - 1;          // ring class count (center counts itself in box)
            int ccorr = bgl - good;      // ring corr count
            int isc = (lab2 < 2) && edge;
            int cal = isc && (ccls >= 1);
            int mse = isc && good && (ccorr >= 1);
            int idx = o*4 + j;
            wq[idx] = mse ? (1.0f / ((float)ccorr + 1e-5f)) : 0.0f;
            labbits  |= ((unsigned)(lab2 & 1)) << idx;
            mse0bits |= ((unsigned)(mse & (lab2 == 0))) << idx;
            mse1bits |= ((unsigned)(mse & (lab2 == 1))) << idx;
            ccal0 += cal & (lab2 == 0);  ccal1 += cal & (lab2 == 1);
            cms0  += mse & (lab2 == 0);  cms1  += mse & (lab2 == 1);
        }
    }

    // global cal/mse counts: only chunk==0 blocks contribute (each pixel once)
    if (chunk == 0) {
        for (int off = 32; off > 0; off >>= 1) {
            ccal0 += __shfl_down(ccal0, off, 64);
            ccal1 += __shfl_down(ccal1, off, 64);
            cms0  += __shfl_down(cms0,  off, 64);
            cms1  += __shfl_down(cms1,  off, 64);
        }
        if (l == 0) {
            atomicAdd(&cnts[0], (unsigned)ccal0);
            atomicAdd(&cnts[1], (unsigned)ccal1);
            atomicAdd(&cnts[2], (unsigned)cms0);
            atomicAdd(&cnts[3], (unsigned)cms1);
        }
    }

    // ---- channel loop: 2-deep software pipeline, DPP horizontal, pure-register vertical ----
    unsigned int rowok = 0;
    #pragma unroll
    for (int rr = 0; rr < 8; rr++)
        if ((unsigned)(rbase + rr) < HH) rowok |= 1u << rr;

    const float4* fb = (const float4*)F + (((size_t)(b*CC + chunk*NCH)) << 14);  // 16384 float4/plane
    float acc0 = 0.f, acc1 = 0.f;

    float4 Areg[8], Breg[8];

    #define LOADROWS(dst, ci)                                                    \
        {                                                                        \
            const float4* pl = fb + ((size_t)(ci) << 14);                        \
            _Pragma("unroll")                                                    \
            for (int rr = 0; rr < 8; rr++) {                                     \
                float4 v = make_float4(0.f, 0.f, 0.f, 0.f);                      \
                if (rowok & (1u << rr)) v = pl[(rbase + rr)*64 + l];             \
                dst[rr] = v;                                                     \
            }                                                                    \
        }

    #define COMPUTE(src)                                                         \
        {                                                                        \
            _Pragma("unroll")                                                    \
            for (int o = 0; o < 4; o++) {                                        \
                float vs0[4] = {0.f,0.f,0.f,0.f}, vs1[4] = {0.f,0.f,0.f,0.f};    \
                _Pragma("unroll")                                                \
                for (int k = 0; k < 5; k++) {                                    \
                    const int row = o + k;                                       \
                    const float4 rv = src[row];                                  \
                    _Pragma("unroll")                                            \
                    for (int j = 0; j < 4; j++) {                                \
                        float x = f4get(rv, j);                                  \
                        vs0[j] = fmaf(fm0[row][j], x, vs0[j]);                   \
                        vs1[j] = fmaf(fm1[row][j], x, vs1[j]);                   \
                    }                                                            \
                }                                                                \
                float S0[4], S1[4];                                              \
                hwin_f(vs0, S0);                                                 \
                hwin_f(vs1, S1);                                                 \
                const float4 ctr = src[o + 2];                                   \
                _Pragma("unroll")                                                \
                for (int j = 0; j < 4; j++) {                                    \
                    const int idx = o*4 + j;                                     \
                    float fc = f4get(ctr, j);                                    \
                    float Ssel = ((labbits >> idx) & 1u) ? S1[j] : S0[j];        \
                    float S = Ssel - fc;                                         \
                    float d = fmaf(-S, wq[idx], fc);                             \
                    float dd = d * d;                                            \
                    acc0 += ((mse0bits >> idx) & 1u) ? dd : 0.f;                 \
                    acc1 += ((mse1bits >> idx) & 1u) ? dd : 0.f;                 \
                }                                                                \
            }                                                                    \
        }

    LOADROWS(Areg, 0);
    #pragma unroll 1
    for (int c = 0; c < NCH; c += 2) {
        LOADROWS(Breg, c + 1);          // prefetch while computing Areg
        COMPUTE(Areg);
        if (c + 2 < NCH) LOADROWS(Areg, c + 2);
        COMPUTE(Breg);
    }
    #undef LOADROWS
    #undef COMPUTE

    // ---- reduce: wave shuffle -> LDS -> double atomics ----
    for (int off = 32; off > 0; off >>= 1) {
        acc0 += __shfl_down(acc0, off, 64);
        acc1 += __shfl_down(acc1, off, 64);
    }
    if (l == 0) { red[w*2] = acc0; red[w*2 + 1] = acc1; }
    __syncthreads();
    if (t == 0) {
        float a0 = red[0] + red[2] + red[4] + red[6];
        float a1 = red[1] + red[3] + red[5] + red[7];
        atomicAdd(&lsum[0], (double)a0);
        atomicAdd(&lsum[1], (double)a1);
    }
}

// ---------------- kernel 3: finalize scalar ----------------
__global__ void k_final(const double* __restrict__ lsum,
                        const unsigned int* __restrict__ cnts, float* out) {
    if (threadIdx.x == 0 && blockIdx.x == 0) {
        float total = 0.f, ncls = 0.f;
        for (int c = 0; c < 2; c++) {
            double num = lsum[c];
            unsigned int calc = cnts[c], msec = cnts[2 + c];
            float denom = fmaxf((float)msec * (float)CC, 1.0f);
            float lc = (float)(num / (double)denom);
            if (calc >= 1u && msec >= 1u) { total += lc; ncls += 1.f; }
        }
        out[0] = (ncls == 0.f) ? total : total / fmaxf(ncls, 1.f);
    }
}

extern "C" void kernel_launch(void* const* d_in, const int* in_sizes, int n_in,
                              void* d_out, int out_size, void* d_ws, size_t ws_size,
                              hipStream_t stream) {
    const float* feats = (const float*)d_in[0];        // [4,256,256,256] fp32
    const float* cls   = (const float*)d_in[1];        // [4,2,256,256] fp32
    const int*   gt    = (const int*)d_in[2];          // [4,256,256] int32
    double* lsum = (double*)d_ws;                      // [0,16)
    unsigned int* cnts = (unsigned int*)((char*)d_ws + 16);  // [16,32)
    unsigned char* code = (unsigned char*)d_ws + 64;   // B*H*W bytes
    float* out = (float*)d_out;

    const int npix = BB*HH*WW;
    k_init<<<1, 64, 0, stream>>>((unsigned int*)d_ws);
    k_code<<<npix/256, 256, 0, stream>>>(cls, gt, code);
    k_loss<<<BB*NTILES*NCHUNKS, 256, 0, stream>>>(feats, code, lsum, cnts);
    k_final<<<1, 64, 0, stream>>>(lsum, cnts, out);
}

// Round 4
// 382.010 us; speedup vs baseline: 1.6317x; 1.6317x over previous
//
#include <hip/hip_runtime.h>
#include <stdint.h>

#define BB 4
#define CC 256
#define HH 256
#define WW 256
#define TH 16                 // output rows per block
#define TR 20                 // rows incl 2+2 halo
#define NCH 16                // channels per block
#define NTILES (HH/TH)        // 16
#define NCHUNKS (CC/NCH)      // 16

// ---------------- kernel 1: per-pixel code byte + accumulator zeroing ----------------
__global__ void k_code(const float* __restrict__ cls, const int* __restrict__ gt,
                       unsigned char* __restrict__ code, unsigned int* __restrict__ acc) {
    int i = blockIdx.x * 256 + threadIdx.x;        // [0, B*H*W)
    if (blockIdx.x == 0 && threadIdx.x < 8) acc[threadIdx.x] = 0;  // lsum(2 dbl)+cnts(4 u32)
    int w = i & 255, h = (i >> 8) & 255;
    int b = i >> 16;
    int g = gt[i];
    float c0 = cls[((b*2 + 0)*HH + h)*WW + w];
    float c1 = cls[((b*2 + 1)*HH + h)*WW + w];
    int pred = (c1 > c0) ? 1 : 0;                  // jnp.argmax tie -> 0
    int ud = (h < HH-5) ? (gt[i + 5*WW] != g) : 0; // pad at END of axis (matches jnp.pad)
    int lr = (w < WW-5) ? (gt[i + 5] != g) : 0;
    int edge = (ud | lr | (g == -1)) ? 1 : 0;
    int lab = (g == 0) ? 0 : ((g == 1) ? 1 : 2);
    int good = (lab < 2 && pred == g) ? 1 : 0;
    code[i] = (unsigned char)(lab | (good << 2) | (edge << 3));
}

// ---- DPP halo exchange (pure VALU, bound_ctrl=0-fill at wave edges) ----
__device__ __forceinline__ float dpp_from_left(float x) {     // lane l-1's value; lane0 -> 0
    int r = __builtin_amdgcn_update_dpp(0, __builtin_bit_cast(int, x), 0x138, 0xf, 0xf, true);
    return __builtin_bit_cast(float, r);
}
__device__ __forceinline__ float dpp_from_right(float x) {    // lane l+1's value; lane63 -> 0
    int r = __builtin_amdgcn_update_dpp(0, __builtin_bit_cast(int, x), 0x130, 0xf, 0xf, true);
    return __builtin_bit_cast(float, r);
}
__device__ __forceinline__ int dpp_from_left_i(int x) {
    return __builtin_amdgcn_update_dpp(0, x, 0x138, 0xf, 0xf, true);
}
__device__ __forceinline__ int dpp_from_right_i(int x) {
    return __builtin_amdgcn_update_dpp(0, x, 0x130, 0xf, 0xf, true);
}

__device__ __forceinline__ float f4get(const float4& v, int j) {
    switch (j) { case 0: return v.x; case 1: return v.y; case 2: return v.z; default: return v.w; }
}

// horizontal 5-window sums over 4 cols/lane (cols 4l..4l+3), halo via DPP
__device__ __forceinline__ void hwin_f(const float* vs, float* S) {
    float eL0 = dpp_from_left(vs[2]);    // col 4l-2
    float eL1 = dpp_from_left(vs[3]);    // col 4l-1
    float eR0 = dpp_from_right(vs[0]);   // col 4l+4
    float eR1 = dpp_from_right(vs[1]);   // col 4l+5
    float m = vs[1] + vs[2];
    float core = vs[0] + m;
    float c2 = m + vs[3];
    S[0] = core + eL0 + eL1;
    S[1] = core + vs[3] + eL1;
    S[2] = core + vs[3] + eR0;
    S[3] = c2 + eR0 + eR1;
}

__device__ __forceinline__ void hwin_i(const int* vs, int* S) {
    int eL0 = dpp_from_left_i(vs[2]);
    int eL1 = dpp_from_left_i(vs[3]);
    int eR0 = dpp_from_right_i(vs[0]);
    int eR1 = dpp_from_right_i(vs[1]);
    int m = vs[1] + vs[2];
    int core = vs[0] + m;
    int c2 = m + vs[3];
    S[0] = core + eL0 + eL1;
    S[1] = core + vs[3] + eL1;
    S[2] = core + vs[3] + eR0;
    S[3] = c2 + eR0 + eR1;
}

// ---------------- kernel 2: the heavy pass (also computes global counts on chunk==0) ----
// grid = B * NTILES * NCHUNKS = 4*16*16 = 1024 blocks, 256 threads.
// wave w: output rows R0+4w..R0+4w+3; lane l: cols 4l..4l+3 (full 256-wide row per wave).
__global__ __launch_bounds__(256) void k_loss(const float* __restrict__ F,
                                              const unsigned char* __restrict__ code,
                                              double* __restrict__ lsum,
                                              unsigned int* __restrict__ cnts) {
    __shared__ unsigned int csh[TR*64];   // code tile, 20 rows x 256 bytes
    __shared__ float red[8];
    const int t = threadIdx.x, w = t >> 6, l = t & 63;
    const int bx = blockIdx.x;
    const int chunk = bx & (NCHUNKS - 1);
    const int tile = (bx >> 4) & (NTILES - 1);
    const int b = bx >> 8;
    const int R0 = tile * TH;

    // ---- stage code tile; out-of-image rows get lab=2 (contributes nothing) ----
    for (int idx = t; idx < TR*64; idx += 256) {
        int rr = idx >> 6, grow = R0 - 2 + rr;
        unsigned int v = 0x02020202u;
        if ((unsigned)grow < HH) v = ((const unsigned int*)code)[(b*HH + grow)*64 + (idx & 63)];
        csh[idx] = v;
    }
    __syncthreads();

    const int rbase = R0 + 4*w - 2;   // wave's first input row (global)

    // ---- per-thread mask build: signed mask sm = +1(c0&good) / -1(c1&good) / 0 ----
    float sm[8][4];
    unsigned int mgd[8], mcls[8];     // bit masks: good-class (bits0-3 c0, 4-7 c1), class
    unsigned int cw2[4];              // center rows' raw code words (rows 2..5)
    #pragma unroll
    for (int rr = 0; rr < 8; rr++) {
        unsigned int u = csh[(4*w + rr)*64 + l];
        unsigned int mg = 0, mc = 0;
        #pragma unroll
        for (int j = 0; j < 4; j++) {
            unsigned int q = (u >> (8*j)) & 255u;
            unsigned int lab2 = q & 3u, good = (q >> 2) & 1u;
            unsigned int c0 = (lab2 == 0u) ? 1u : 0u;
            unsigned int c1 = (lab2 == 1u) ? 1u : 0u;
            mg |= (c0 & good) << j;
            mg |= (c1 & good) << (4 + j);
            mc |= c0 << j;
            mc |= c1 << (4 + j);
            sm[rr][j] = (float)(int)((c0 & good)) - (float)(int)((c1 & good));
        }
        mgd[rr] = mg; mcls[rr] = mc;
        if (rr >= 2 && rr <= 5) cw2[rr - 2] = u;
    }

    // ---- counts / wq precompute (channel-invariant) ----
    float wq[16];
    unsigned int mse0bits = 0, mse1bits = 0, labbits = 0;
    int ccal0 = 0, ccal1 = 0, cms0 = 0, cms1 = 0;
    #pragma unroll
    for (int o = 0; o < 4; o++) {
        int vg0[4] = {0,0,0,0}, vg1[4] = {0,0,0,0}, vc0[4] = {0,0,0,0}, vc1[4] = {0,0,0,0};
        #pragma unroll
        for (int k = 0; k < 5; k++) {
            unsigned int mg = mgd[o+k], mc = mcls[o+k];
            #pragma unroll
            for (int j = 0; j < 4; j++) {
                vg0[j] += (mg >> j) & 1;  vg1[j] += (mg >> (4+j)) & 1;
                vc0[j] += (mc >> j) & 1;  vc1[j] += (mc >> (4+j)) & 1;
            }
        }
        int bg0[4], bg1[4], bc0[4], bc1[4];
        hwin_i(vg0, bg0); hwin_i(vg1, bg1);
        hwin_i(vc0, bc0); hwin_i(vc1, bc1);
        #pragma unroll
        for (int j = 0; j < 4; j++) {
            unsigned int q = (cw2[o] >> (8*j)) & 255u;
            int lab2 = q & 3, good = (q >> 2) & 1, edge = (q >> 3) & 1;
            int bcl = (lab2 == 1) ? bc1[j] : bc0[j];
            int bgl = (lab2 == 1) ? bg1[j] : bg0[j];
            int ccls = bcl - 1;          // ring class count (center counts itself in box)
            int ccorr = bgl - good;      // ring corr count
            int isc = (lab2 < 2) && edge;
            int cal = isc && (ccls >= 1);
            int mse = isc && good && (ccorr >= 1);
            int idx = o*4 + j;
            wq[idx] = mse ? (1.0f / ((float)ccorr + 1e-5f)) : 0.0f;
            labbits  |= ((unsigned)(lab2 & 1)) << idx;
            mse0bits |= ((unsigned)(mse & (lab2 == 0))) << idx;
            mse1bits |= ((unsigned)(mse & (lab2 == 1))) << idx;
            ccal0 += cal & (lab2 == 0);  ccal1 += cal & (lab2 == 1);
            cms0  += mse & (lab2 == 0);  cms1  += mse & (lab2 == 1);
        }
    }

    // global cal/mse counts: only chunk==0 blocks contribute (each pixel once)
    if (chunk == 0) {
        for (int off = 32; off > 0; off >>= 1) {
            ccal0 += __shfl_down(ccal0, off, 64);
            ccal1 += __shfl_down(ccal1, off, 64);
            cms0  += __shfl_down(cms0,  off, 64);
            cms1  += __shfl_down(cms1,  off, 64);
        }
        if (l == 0) {
            atomicAdd(&cnts[0], (unsigned)ccal0);
            atomicAdd(&cnts[1], (unsigned)ccal1);
            atomicAdd(&cnts[2], (unsigned)cms0);
            atomicAdd(&cnts[3], (unsigned)cms1);
        }
    }

    // ---- channel loop: row-stream pipeline, ring of 8, 3-row lookahead ----
    unsigned int rowok = 0;
    #pragma unroll
    for (int rr = 0; rr < 8; rr++)
        if ((unsigned)(rbase + rr) < HH) rowok |= 1u << rr;

    const float4* fb = (const float4*)F + (((size_t)(b*CC + chunk*NCH)) << 14);  // 16384 f4/plane
    float acc0 = 0.f, acc1 = 0.f;
    float4 ring[8];   // slot = input-row index (0..7); all indices literal after unroll

    #define LOADP(slot, pl, rr)                                                  \
        {                                                                        \
            float4 v = make_float4(0.f, 0.f, 0.f, 0.f);                          \
            if (rowok & (1u << (rr))) v = (pl)[(rbase + (rr))*64 + l];           \
            ring[(slot)] = v;                                                    \
        }

    #define COMP(o)                                                              \
        {                                                                        \
            float vsg[4] = {0.f,0.f,0.f,0.f}, vse[4] = {0.f,0.f,0.f,0.f};        \
            _Pragma("unroll")                                                    \
            for (int k = 0; k < 5; k++) {                                        \
                const float4 rv = ring[(o) + k];                                 \
                _Pragma("unroll")                                                \
                for (int j = 0; j < 4; j++) {                                    \
                    float x = f4get(rv, j);                                      \
                    float s = sm[(o) + k][j];                                    \
                    vse[j] = fmaf(s, x, vse[j]);                                 \
                    vsg[j] = fmaf(fabsf(s), x, vsg[j]);                          \
                }                                                                \
            }                                                                    \
            float G[4], E[4];                                                    \
            hwin_f(vsg, G);                                                      \
            hwin_f(vse, E);                                                      \
            const float4 ctr = ring[(o) + 2];                                    \
            _Pragma("unroll")                                                    \
            for (int j = 0; j < 4; j++) {                                        \
                const int idx = (o)*4 + j;                                       \
                float fc = f4get(ctr, j);                                        \
                float Es = ((labbits >> idx) & 1u) ? -E[j] : E[j];               \
                float U = G[j] + Es;            /* 2*box-sum of own class */     \
                float v = fmaf(U, -0.5f, fc);   /* fc - box = -(ring sum) */     \
                float d = fmaf(v, wq[idx], fc); /* fc - ring*wq */               \
                float dd = d * d;                                                \
                acc0 += ((mse0bits >> idx) & 1u) ? dd : 0.f;                     \
                acc1 += ((mse1bits >> idx) & 1u) ? dd : 0.f;                     \
            }                                                                    \
        }

    // prologue: rows 0..2 of channel 0
    {
        const float4* pl0 = fb;
        LOADP(0, pl0, 0); LOADP(1, pl0, 1); LOADP(2, pl0, 2);
    }
    #pragma unroll 1
    for (int c = 0; c < NCH; c++) {
        const float4* plA = fb + ((size_t)c << 14);
        const float4* plB = plA + (size_t)(1 << 14);
        const bool nx = (c + 1 < NCH);
        LOADP(3, plA, 3);
        LOADP(4, plA, 4);
        LOADP(5, plA, 5);
        LOADP(6, plA, 6);
        LOADP(7, plA, 7);
        COMP(0);
        if (nx) LOADP(0, plB, 0);
        COMP(1);
        if (nx) LOADP(1, plB, 1);
        COMP(2);
        if (nx) LOADP(2, plB, 2);
        COMP(3);
    }
    #undef LOADP
    #undef COMP

    // ---- reduce: wave shuffle -> LDS -> double atomics ----
    for (int off = 32; off > 0; off >>= 1) {
        acc0 += __shfl_down(acc0, off, 64);
        acc1 += __shfl_down(acc1, off, 64);
    }
    if (l == 0) { red[w*2] = acc0; red[w*2 + 1] = acc1; }
    __syncthreads();
    if (t == 0) {
        float a0 = red[0] + red[2] + red[4] + red[6];
        float a1 = red[1] + red[3] + red[5] + red[7];
        atomicAdd(&lsum[0], (double)a0);
        atomicAdd(&lsum[1], (double)a1);
    }
}

// ---------------- kernel 3: finalize scalar ----------------
__global__ void k_final(const double* __restrict__ lsum,
                        const unsigned int* __restrict__ cnts, float* out) {
    if (threadIdx.x == 0 && blockIdx.x == 0) {
        float total = 0.f, ncls = 0.f;
        for (int c = 0; c < 2; c++) {
            double num = lsum[c];
            unsigned int calc = cnts[c], msec = cnts[2 + c];
            float denom = fmaxf((float)msec * (float)CC, 1.0f);
            float lc = (float)(num / (double)denom);
            if (calc >= 1u && msec >= 1u) { total += lc; ncls += 1.f; }
        }
        out[0] = (ncls == 0.f) ? total : total / fmaxf(ncls, 1.f);
    }
}

extern "C" void kernel_launch(void* const* d_in, const int* in_sizes, int n_in,
                              void* d_out, int out_size, void* d_ws, size_t ws_size,
                              hipStream_t stream) {
    const float* feats = (const float*)d_in[0];        // [4,256,256,256] fp32
    const float* cls   = (const float*)d_in[1];        // [4,2,256,256] fp32
    const int*   gt    = (const int*)d_in[2];          // [4,256,256] int32
    double* lsum = (double*)d_ws;                      // [0,16)
    unsigned int* cnts = (unsigned int*)((char*)d_ws + 16);  // [16,32)
    unsigned char* code = (unsigned char*)d_ws + 64;   // B*H*W bytes
    float* out = (float*)d_out;

    const int npix = BB*HH*WW;
    k_code<<<npix/256, 256, 0, stream>>>(cls, gt, code, (unsigned int*)d_ws);
    k_loss<<<BB*NTILES*NCHUNKS, 256, 0, stream>>>(feats, code, lsum, cnts);
    k_final<<<1, 64, 0, stream>>>(lsum, cnts, out);
}